// Round 6
// baseline (264.768 us; speedup 1.0000x reference)
//
#include <hip/hip_runtime.h>

typedef unsigned short u16;
typedef unsigned int u32;
typedef __bf16 bf16x8 __attribute__((ext_vector_type(8)));
typedef float f32x4 __attribute__((ext_vector_type(4)));
typedef float f32x16 __attribute__((ext_vector_type(16)));

extern "C" __device__ float __ocml_native_exp2_f32(float);

// workspace offsets in u16 elements
#define WT_HI_E  ((size_t)0)             // 3 x 1M
#define WT_LO_E  ((size_t)3 << 20)
#define X_HI_E   ((size_t)6 << 20)       // 4M each below
#define X_LO_E   ((size_t)10 << 20)
#define Q_HI_E   ((size_t)14 << 20)
#define Q_LO_E   ((size_t)18 << 20)
#define K_HI_E   ((size_t)22 << 20)      // [hb][s][64] d-chunk-XOR-swizzled
#define K_LO_E   ((size_t)26 << 20)
#define V_HI_E   ((size_t)30 << 20)      // V^T [hb][d][2048], s-chunk-XOR-swizzled per 64-key block
// split-KV partials (regions dead after k_proj): half1 raw-O f32 at ws byte 0
// (16 MiB, WT+X region), per-query (m,l) float2 at ws byte 17 MiB (1 MiB).
#define ML_BYTE  (17u << 20)

__device__ __forceinline__ u16 bf16_rne(float x) {
  u32 u = __float_as_uint(x);
  u32 r = (u + 0x7fffu + ((u >> 16) & 1u)) >> 16;
  return (u16)r;
}
__device__ __forceinline__ float bf16_f(u16 h) {
  return __uint_as_float(((u32)h) << 16);
}
// native hw convert (rounding mode irrelevant for hi/lo splits: lo absorbs it)
__device__ __forceinline__ u16 f2bf(float x) {
  __bf16 b = (__bf16)x;
  return __builtin_bit_cast(u16, b);
}

__device__ __forceinline__ void gload16(const u16* g, u16* l) {
  __builtin_amdgcn_global_load_lds(
      (const __attribute__((address_space(1))) void*)g,
      (__attribute__((address_space(3))) void*)l, 16, 0, 0);
}

// ---------------- fused input prep: X split + W transpose/split ----------------
__global__ __launch_bounds__(256) void k_split(const float* __restrict__ X,
                                               const float* __restrict__ w0,
                                               const float* __restrict__ w1,
                                               const float* __restrict__ w2,
                                               u16* __restrict__ ws) {
  int bid = blockIdx.x;
  if (bid < 2048) {
    u16* xh = ws + X_HI_E;
    u16* xl = ws + X_LO_E;
    size_t i = ((size_t)bid * 256 + threadIdx.x) * 8;
    float4 a = *(const float4*)(X + i);
    float4 b = *(const float4*)(X + i + 4);
    float v[8] = {a.x, a.y, a.z, a.w, b.x, b.y, b.z, b.w};
    u32 Hh[4], Ll[4];
#pragma unroll
    for (int j = 0; j < 4; j++) {
      u16 h0 = f2bf(v[2 * j]);
      u16 h1 = f2bf(v[2 * j + 1]);
      u16 l0 = f2bf(v[2 * j] - bf16_f(h0));
      u16 l1 = f2bf(v[2 * j + 1] - bf16_f(h1));
      Hh[j] = (u32)h0 | ((u32)h1 << 16);
      Ll[j] = (u32)l0 | ((u32)l1 << 16);
    }
    *(uint4*)(xh + i) = make_uint4(Hh[0], Hh[1], Hh[2], Hh[3]);
    *(uint4*)(xl + i) = make_uint4(Ll[0], Ll[1], Ll[2], Ll[3]);
  } else {
    int wb = bid - 2048;                    // [0,768): 256 64x64 tiles x 3 mats
    int z = wb >> 8;
    int rem = wb & 255;
    int by = (rem >> 4) * 64, bx = (rem & 15) * 64;
    const float* W = (z == 0) ? w0 : ((z == 1) ? w1 : w2);
    u16* th = ws + WT_HI_E + (size_t)z * (1u << 20);
    u16* tl = ws + WT_LO_E + (size_t)z * (1u << 20);
    __shared__ float tile[64][65];
    int tx = threadIdx.x & 15, ty = threadIdx.x >> 4;  // 16 x 16
#pragma unroll
    for (int i = 0; i < 4; i++) {
      int r = ty + i * 16;
      float4 v = *(const float4*)(W + (size_t)(by + r) * 1024 + bx + tx * 4);
      tile[r][tx * 4 + 0] = v.x;
      tile[r][tx * 4 + 1] = v.y;
      tile[r][tx * 4 + 2] = v.z;
      tile[r][tx * 4 + 3] = v.w;
    }
    __syncthreads();
    // transposed write: thread owns 8 consecutive k for one output row n
#pragma unroll
    for (int p = 0; p < 2; p++) {
      int t = threadIdx.x + 256 * p;
      int kc = t & 7, nl = t >> 3;  // kc: chunk of 8 k, nl in [0,64)
      u32 Hh[4], Ll[4];
#pragma unroll
      for (int u = 0; u < 4; u++) {
        float v0 = tile[kc * 8 + 2 * u][nl];      // = W[by+k][bx+nl]
        float v1 = tile[kc * 8 + 2 * u + 1][nl];
        u16 h0 = f2bf(v0);
        u16 h1 = f2bf(v1);
        u16 l0 = f2bf(v0 - bf16_f(h0));
        u16 l1 = f2bf(v1 - bf16_f(h1));
        Hh[u] = (u32)h0 | ((u32)h1 << 16);
        Ll[u] = (u32)l0 | ((u32)l1 << 16);
      }
      size_t o = (size_t)(bx + nl) * 1024 + by + kc * 8;
      *(uint4*)(th + o) = make_uint4(Hh[0], Hh[1], Hh[2], Hh[3]);
      *(uint4*)(tl + o) = make_uint4(Ll[0], Ll[1], Ll[2], Ll[3]);
    }
  }
}

// ---------------- projections: Y = X @ W, compensated bf16 MFMA ----------------
// 64(M)x128(N) tiles, grid 1536 = 8 xcd x 8 m x 8 n x 3 z, XCD-affine M.
__global__ __launch_bounds__(256, 4) void k_proj(u16* __restrict__ ws) {
  int id = blockIdx.x;
  int xcd = id & 7;
  int loc = id >> 3;            // 192 per XCD
  int m_loc = loc & 7;          // 8 M-blocks of 64 rows per XCD slice
  int rest = loc >> 3;          // 24 = 8 n x 3 z
  int n_blk = rest & 7, z = rest >> 3;
  int M0 = (xcd * 8 + m_loc) * 64;
  int N0 = n_blk * 128;

  const u16* Xh = ws + X_HI_E;
  const u16* Xl = ws + X_LO_E;
  const u16* Wh = ws + WT_HI_E + (size_t)z * (1u << 20);
  const u16* Wl = ws + WT_LO_E + (size_t)z * (1u << 20);
  u16* dsth = ws + ((z == 0) ? Q_HI_E : ((z == 1) ? K_HI_E : V_HI_E));
  u16* dstl = (z == 0) ? (ws + Q_LO_E) : ((z == 1) ? (ws + K_LO_E) : (u16*)0);

  __shared__ u16 smem[12288];  // 24 KB: staging in main loop, epilogue after
  u16* sXh = smem;             // 64x32
  u16* sXl = smem + 2048;
  u16* sWh = smem + 4096;      // 128x32
  u16* sWl = smem + 8192;

  int tid = threadIdx.x, lane = tid & 63, w = tid >> 6;
  int quad = lane >> 4, l16 = lane & 15;
  int mb = (w & 1) * 32, nb = (w >> 1) * 64;

  const f32x4 z4 = {0.f, 0.f, 0.f, 0.f};
  f32x4 acc[4][2];             // [d-tile][s-tile] for all z
#pragma unroll
  for (int j = 0; j < 4; j++)
#pragma unroll
    for (int i = 0; i < 2; i++) acc[j][i] = z4;

  int xrow = tid >> 2, xq8 = tid & 3;  // X staging: one 16B chunk/thread

  for (int kk = 0; kk < 1024; kk += 32) {
    __syncthreads();
    {
      size_t gx = (size_t)(M0 + xrow) * 1024 + kk + xq8 * 8;
      gload16(Xh + gx, &sXh[(size_t)(w * 16) * 32]);
      if (z != 2) gload16(Xl + gx, &sXl[(size_t)(w * 16) * 32]);
#pragma unroll
      for (int j = 0; j < 2; j++) {
        int c = tid + 256 * j;
        int row = c >> 2, q8 = c & 3;
        size_t gw = (size_t)(N0 + row) * 1024 + kk + q8 * 8;
        gload16(Wh + gw, &sWh[(size_t)(j * 64 + w * 16) * 32]);
        if (z != 2) gload16(Wl + gw, &sWl[(size_t)(j * 64 + w * 16) * 32]);
      }
    }
    __syncthreads();
    bf16x8 ah[2], bh[4];
#pragma unroll
    for (int i = 0; i < 2; i++)
      ah[i] = *(const bf16x8*)&sXh[(mb + i * 16 + l16) * 32 + quad * 8];
#pragma unroll
    for (int j = 0; j < 4; j++)
      bh[j] = *(const bf16x8*)&sWh[(nb + j * 16 + l16) * 32 + quad * 8];
    if (z != 2) {
      bf16x8 al[2], bl[4];
#pragma unroll
      for (int i = 0; i < 2; i++)
        al[i] = *(const bf16x8*)&sXl[(mb + i * 16 + l16) * 32 + quad * 8];
#pragma unroll
      for (int j = 0; j < 4; j++)
        bl[j] = *(const bf16x8*)&sWl[(nb + j * 16 + l16) * 32 + quad * 8];
      // swapped operands: C row <- W(d), C col <- X(s)
#pragma unroll
      for (int j = 0; j < 4; j++)
#pragma unroll
        for (int i = 0; i < 2; i++) {
          f32x4 c0 = acc[j][i];
          c0 = __builtin_amdgcn_mfma_f32_16x16x32_bf16(bh[j], ah[i], c0, 0, 0, 0);
          c0 = __builtin_amdgcn_mfma_f32_16x16x32_bf16(bh[j], al[i], c0, 0, 0, 0);
          c0 = __builtin_amdgcn_mfma_f32_16x16x32_bf16(bl[j], ah[i], c0, 0, 0, 0);
          acc[j][i] = c0;
        }
    } else {
#pragma unroll
      for (int j = 0; j < 4; j++)
#pragma unroll
        for (int i = 0; i < 2; i++)
          acc[j][i] = __builtin_amdgcn_mfma_f32_16x16x32_bf16(ah[i], bh[j], acc[j][i], 0, 0, 0);
    }
  }

  // ---- dense epilogue via LDS (staging area is dead; barrier fences it) ----
  __syncthreads();
  int b = M0 >> 11, S0 = M0 & 2047;        // batch, 64-aligned s-base of block

  if (z != 2) {
    // per-wave-private 4KB region: 32(s) x 64(d) tile, d-chunk XOR swizzle
    u16* my = smem + (size_t)w * 2048;
    int hh = (N0 + nb) >> 6;
    int sbase = S0 + mb;
    float qscale = (z == 0) ? (0.125f * 1.4426950408889634f) : 1.0f;
#pragma unroll
    for (int pass = 0; pass < 2; pass++) {
      u16* dst = pass ? dstl : dsth;
#pragma unroll
      for (int j = 0; j < 4; j++)
#pragma unroll
        for (int i = 0; i < 2; i++) {
          int dl = j * 16 + quad * 4;   // d_local: 4 consecutive (one uint2)
          int sl = i * 16 + l16;        // s_local in [0,32)
          u16 e[4];
#pragma unroll
          for (int r = 0; r < 4; r++) {
            float y = acc[j][i][r] * qscale;
            u16 hv = bf16_rne(y);
            e[r] = pass ? bf16_rne(y - bf16_f(hv)) : hv;
          }
          int elem = sl * 64 + (((dl >> 3) ^ (sl & 7)) << 3) + (dl & 7);
          *(uint2*)&my[elem] = make_uint2((u32)e[0] | ((u32)e[1] << 16),
                                          (u32)e[2] | ((u32)e[3] << 16));
        }
#pragma unroll
      for (int t = 0; t < 4; t++) {
        int sr = (lane >> 3) + t * 8;
        int p = lane & 7;
        int rc = (z == 1) ? p : (p ^ (sr & 7));
        uint4 v = *(const uint4*)&my[sr * 64 + rc * 8];
        size_t o = ((size_t)(hh * 2 + b) * 2048 + sbase + sr) * 64 + p * 8;
        *(uint4*)&dst[o] = v;
      }
    }
  } else {
    // V: block-shared [half][64 d][64 s] tiles (16 KB), s-chunk XOR swizzle
#pragma unroll
    for (int j = 0; j < 4; j++)
#pragma unroll
      for (int i = 0; i < 2; i++) {
        int dl = j * 16 + l16;                       // d within 64
        int s64 = mb + i * 16 + quad * 4;            // s within 64 (both waves)
        u16 e[4];
#pragma unroll
        for (int r = 0; r < 4; r++) e[r] = bf16_rne(acc[j][i][r]);
        int cp = ((s64 >> 3) & 7) ^ (dl & 7);
        int elem = (w >> 1) * 4096 + dl * 64 + (cp << 3) + (s64 & 7);
        *(uint2*)&smem[elem] = make_uint2((u32)e[0] | ((u32)e[1] << 16),
                                          (u32)e[2] | ((u32)e[3] << 16));
      }
    __syncthreads();  // both waves of a half wrote all s of its d-rows
    int half = w >> 1;
    int hh = (N0 + half * 64) >> 6;
#pragma unroll
    for (int t = 0; t < 4; t++) {
      int dr = (w & 1) * 32 + (lane >> 3) + t * 8;   // d-row within the half
      int p = lane & 7;
      uint4 v = *(const uint4*)&smem[half * 4096 + dr * 64 + p * 8];
      size_t o = ((size_t)(hh * 2 + b) * 64 + dr) * 2048 + S0 + p * 8;
      *(uint4*)&dsth[o] = v;
    }
  }
}

// ---------------- flash attention: split-KV (2 halves), round-3 body ----------------
// grid 1024 = 32 hb x 16 qb x 2 key-halves; 4 waves/block, 32 q/wave.
// LDS 32 KB (K-hi + V^T dbuf only) -> 4 blocks/CU resident = 16 waves/CU (2x TLP).
// K-lo fragments gathered per-lane from global (L2-resident, 3 MB/XCD), issued
// BEFORE the stage loads so the compiler's auto-vmcnt drains them without
// draining the tile-(it+1) prefetch. Each half writes raw (unnormalized) O +
// per-query (m,l); k_merge combines.
__global__ __launch_bounds__(256, 4) void k_attn(u16* __restrict__ ws,
                                                 float* __restrict__ out) {
  const u16* Qh = ws + Q_HI_E;
  const u16* Ql = ws + Q_LO_E;
  const u16* Kh = ws + K_HI_E;
  const u16* Kl = ws + K_LO_E;
  const u16* Vt = ws + V_HI_E;

  __shared__ u16 sKh[2][64][64], sVt[2][64][64];  // 32 KB

  int id = blockIdx.x;
  int hb = id & 31, qb = (id >> 5) & 15, half = id >> 9;  // id&7 = XCD affinity
  int kbase = half << 10;                                 // key offset 0 / 1024
  int tid = threadIdx.x, w = tid >> 6, lane = tid & 63;
  int l31 = lane & 31, h = lane >> 5;
  size_t base = (size_t)hb * (2048 * 64);
  int qw0 = qb * 128 + w * 32;

  int srow = lane >> 3, sch = lane & 7;  // staging: 8 rows x 128B per wave-instr

  auto stage = [&](int buf, int t) {
    int kt = kbase + t * 64;
#pragma unroll
    for (int b2 = 0; b2 < 2; b2++) {
      int rr = w * 16 + b2 * 8;
      size_t kg = base + (size_t)(kt + rr + srow) * 64 + sch * 8;
      gload16(Kh + kg, &sKh[buf][rr][0]);
      size_t vg = base + (size_t)(rr + srow) * 2048 + kt + sch * 8;
      gload16(Vt + vg, &sVt[buf][rr][0]);
    }
  };

  stage(0, 0);

  // Q B-operand frags (n = query = l31, k-step ks: d = ks*16 + h*8)
  bf16x8 qh[4], ql[4];
#pragma unroll
  for (int ks = 0; ks < 4; ks++) {
    size_t off = base + (size_t)(qw0 + l31) * 64 + ks * 16 + h * 8;
    qh[ks] = *(const bf16x8*)(Qh + off);
    ql[ks] = *(const bf16x8*)(Ql + off);
  }

  f32x16 o[2];
#pragma unroll
  for (int i = 0; i < 16; i++) { o[0][i] = 0.f; o[1][i] = 0.f; }
  float mr = -1e30f, lr = 0.f;

  // A-operand read from a swizzled tile: row = mt*32 + l31, chunk = (ks*2+h)^(row&7)
  auto rdA = [&](const u16 t[64][64], int mt, int ks) -> bf16x8 {
    int ch = ((ks * 2 + h) ^ (l31 & 7)) * 8;
    return *(const bf16x8*)&t[mt * 32 + l31][ch];
  };

  for (int it = 0; it < 16; it++) {
    __syncthreads();
    // K-lo per-lane gathers for THIS tile (issued first -> oldest in vmcnt
    // order; waiting on them leaves the stage(it+1) loads in flight).
    int kt = kbase + it * 64;
    bf16x8 klf[8];
#pragma unroll
    for (int ks = 0; ks < 4; ks++)
#pragma unroll
      for (int mt = 0; mt < 2; mt++) {
        int row = kt + mt * 32 + l31;
        int c2 = ((ks * 2 + h) ^ (row & 7)) * 8;   // global d-chunk swizzle
        klf[ks * 2 + mt] = *(const bf16x8*)(Kl + base + (size_t)row * 64 + c2);
      }
    if (it + 1 < 16) stage((it + 1) & 1, it + 1);
    int buf = it & 1;

    // S^T = K.Q^T (compensated): hi terms from LDS first (covers Kl L2 latency)
    f32x16 sc[2];
#pragma unroll
    for (int i = 0; i < 16; i++) { sc[0][i] = 0.f; sc[1][i] = 0.f; }
#pragma unroll
    for (int ks = 0; ks < 4; ks++)
#pragma unroll
      for (int mt = 0; mt < 2; mt++) {
        bf16x8 kh = rdA(sKh[buf], mt, ks);
        sc[mt] = __builtin_amdgcn_mfma_f32_32x32x16_bf16(kh, qh[ks], sc[mt], 0, 0, 0);
        sc[mt] = __builtin_amdgcn_mfma_f32_32x32x16_bf16(kh, ql[ks], sc[mt], 0, 0, 0);
      }
#pragma unroll
    for (int ks = 0; ks < 4; ks++)
#pragma unroll
      for (int mt = 0; mt < 2; mt++)
        sc[mt] = __builtin_amdgcn_mfma_f32_32x32x16_bf16(klf[ks * 2 + mt], qh[ks], sc[mt], 0, 0, 0);

    // online softmax (log2 domain): per-lane scalar stats, 1 shfl max + 1 shfl sum
    float mx = sc[0][0];
#pragma unroll
    for (int i = 0; i < 16; i++) {
      mx = fmaxf(mx, sc[0][i]);
      mx = fmaxf(mx, sc[1][i]);
    }
    mx = fmaxf(mx, __shfl_xor(mx, 32));
    float mnew = fmaxf(mr, mx);
    float alpha = __ocml_native_exp2_f32(mr - mnew);
    mr = mnew;
    float rs = 0.f;
    u32 pk[2][8];
#pragma unroll
    for (int t = 0; t < 2; t++)
#pragma unroll
      for (int i = 0; i < 8; i++) {
        float p0 = __ocml_native_exp2_f32(sc[t][2 * i] - mnew);
        float p1 = __ocml_native_exp2_f32(sc[t][2 * i + 1] - mnew);
        rs += p0 + p1;
        u32 a = __float_as_uint(p0) + 0x8000u;
        u32 b = __float_as_uint(p1) + 0x8000u;
        pk[t][i] = __builtin_amdgcn_perm(b, a, 0x07060302u);  // [hi16(a)|hi16(b)]
      }
    rs += __shfl_xor(rs, 32);
    lr = lr * alpha + rs;
#pragma unroll
    for (int i = 0; i < 16; i++) {
      o[0][i] *= alpha;
      o[1][i] *= alpha;
    }

    // O^T += V^T . P^T : B-frag (k=key, n=query) assembled from S^T regs via xor-32
#pragma unroll
    for (int ks = 0; ks < 4; ks++) {
      int t = ks >> 1, c = ks & 1;
      u32 b0 = pk[t][c * 4 + 0], b1 = pk[t][c * 4 + 1];
      u32 b2 = pk[t][c * 4 + 2], b3 = pk[t][c * 4 + 3];
      u32 rA = (u32)__shfl_xor((int)(h ? b0 : b2), 32);
      u32 rB = (u32)__shfl_xor((int)(h ? b1 : b3), 32);
      uint4 fb = h ? make_uint4(rA, rB, b2, b3) : make_uint4(b0, b1, rA, rB);
      bf16x8 pfrag = *(bf16x8*)&fb;
#pragma unroll
      for (int mt = 0; mt < 2; mt++) {
        bf16x8 vb = rdA(sVt[buf], mt, ks);
        o[mt] = __builtin_amdgcn_mfma_f32_32x32x16_bf16(vb, pfrag, o[mt], 0, 0, 0);
      }
    }
  }

  // epilogue: RAW (unnormalized) O; half0 -> out, half1 -> ws byte 0 region.
  float* dst = (half == 0) ? out : (float*)ws;
  size_t grow = (size_t)hb * 2048 + qw0 + l31;
#pragma unroll
  for (int mt = 0; mt < 2; mt++)
#pragma unroll
    for (int g2 = 0; g2 < 4; g2++) {
      int d0 = mt * 32 + g2 * 8 + 4 * h;
      float4 v = make_float4(o[mt][g2 * 4 + 0], o[mt][g2 * 4 + 1],
                             o[mt][g2 * 4 + 2], o[mt][g2 * 4 + 3]);
      *(float4*)(dst + grow * 64 + d0) = v;
    }
  // per-query stats (identical across h by construction): one lane writes
  if (h == 0) {
    float2* ml = (float2*)((char*)ws + ML_BYTE);
    ml[(size_t)half * 65536 + grow] = make_float2(mr, lr);
  }
}

// ---------------- merge the two KV-halves ----------------
// out = (o0*2^(m0-M) + o1*2^(m1-M)) / (l0*2^(m0-M) + l1*2^(m1-M))
__global__ __launch_bounds__(256) void k_merge(u16* __restrict__ ws,
                                               float* __restrict__ out) {
  size_t g = (size_t)blockIdx.x * 256 + threadIdx.x;  // float4 index, 1,048,576 total
  size_t row = g >> 4;                                // hb*2048 + q
  const float2* ml = (const float2*)((const char*)ws + ML_BYTE);
  float2 a = ml[row];
  float2 b = ml[65536 + row];
  float M = fmaxf(a.x, b.x);
  float e0 = __ocml_native_exp2_f32(a.x - M);
  float e1 = __ocml_native_exp2_f32(b.x - M);
  float winv = 1.f / (a.y * e0 + b.y * e1);
  float4 p0 = ((const float4*)out)[g];
  float4 p1 = ((const float4*)(const void*)ws)[g];
  float4 r = make_float4((p0.x * e0 + p1.x * e1) * winv,
                         (p0.y * e0 + p1.y * e1) * winv,
                         (p0.z * e0 + p1.z * e1) * winv,
                         (p0.w * e0 + p1.w * e1) * winv);
  ((float4*)out)[g] = r;
}

extern "C" void kernel_launch(void* const* d_in, const int* in_sizes, int n_in,
                              void* d_out, int out_size, void* d_ws, size_t ws_size,
                              hipStream_t stream) {
  const float* X = (const float*)d_in[0];
  const float* Wq = (const float*)d_in[1];
  const float* Wk = (const float*)d_in[2];
  const float* Wv = (const float*)d_in[3];
  u16* ws = (u16*)d_ws;
  float* out = (float*)d_out;

  k_split<<<dim3(2816), dim3(256), 0, stream>>>(X, Wq, Wk, Wv, ws);
  k_proj<<<dim3(1536), dim3(256), 0, stream>>>(ws);
  k_attn<<<dim3(1024), dim3(256), 0, stream>>>(ws, out);
  k_merge<<<dim3(4096), dim3(256), 0, stream>>>(ws, out);
}

// Round 7
// 241.821 us; speedup vs baseline: 1.0949x; 1.0949x over previous
//
#include <hip/hip_runtime.h>

typedef unsigned short u16;
typedef unsigned int u32;
typedef __bf16 bf16x8 __attribute__((ext_vector_type(8)));
typedef float f32x4 __attribute__((ext_vector_type(4)));
typedef float f32x16 __attribute__((ext_vector_type(16)));

extern "C" __device__ float __ocml_native_exp2_f32(float);

// workspace offsets in u16 elements
#define WT_HI_E  ((size_t)0)             // 3 x 1M
#define WT_LO_E  ((size_t)3 << 20)
#define X_HI_E   ((size_t)6 << 20)       // 4M each below
#define X_LO_E   ((size_t)10 << 20)
#define Q_HI_E   ((size_t)14 << 20)
#define Q_LO_E   ((size_t)18 << 20)
#define K_HI_E   ((size_t)22 << 20)      // [hb][s][64] d-chunk-XOR-swizzled
#define K_LO_E   ((size_t)26 << 20)
#define V_HI_E   ((size_t)30 << 20)      // V^T [hb][d][2048], s-chunk-XOR-swizzled per 64-key block
// split-KV partials (regions dead after k_proj): half1 raw-O f32 at ws byte 0
// (16 MiB, WT+X region), per-query (m,l) float2 at ws byte 17 MiB (1 MiB).
#define ML_BYTE  (17u << 20)

__device__ __forceinline__ u16 bf16_rne(float x) {
  u32 u = __float_as_uint(x);
  u32 r = (u + 0x7fffu + ((u >> 16) & 1u)) >> 16;
  return (u16)r;
}
__device__ __forceinline__ float bf16_f(u16 h) {
  return __uint_as_float(((u32)h) << 16);
}
// native hw convert (rounding mode irrelevant for hi/lo splits: lo absorbs it)
__device__ __forceinline__ u16 f2bf(float x) {
  __bf16 b = (__bf16)x;
  return __builtin_bit_cast(u16, b);
}

__device__ __forceinline__ void gload16(const u16* g, u16* l) {
  __builtin_amdgcn_global_load_lds(
      (const __attribute__((address_space(1))) void*)g,
      (__attribute__((address_space(3))) void*)l, 16, 0, 0);
}

// ---------------- fused input prep: X split + W transpose/split ----------------
__global__ __launch_bounds__(256) void k_split(const float* __restrict__ X,
                                               const float* __restrict__ w0,
                                               const float* __restrict__ w1,
                                               const float* __restrict__ w2,
                                               u16* __restrict__ ws) {
  int bid = blockIdx.x;
  if (bid < 2048) {
    u16* xh = ws + X_HI_E;
    u16* xl = ws + X_LO_E;
    size_t i = ((size_t)bid * 256 + threadIdx.x) * 8;
    float4 a = *(const float4*)(X + i);
    float4 b = *(const float4*)(X + i + 4);
    float v[8] = {a.x, a.y, a.z, a.w, b.x, b.y, b.z, b.w};
    u32 Hh[4], Ll[4];
#pragma unroll
    for (int j = 0; j < 4; j++) {
      u16 h0 = f2bf(v[2 * j]);
      u16 h1 = f2bf(v[2 * j + 1]);
      u16 l0 = f2bf(v[2 * j] - bf16_f(h0));
      u16 l1 = f2bf(v[2 * j + 1] - bf16_f(h1));
      Hh[j] = (u32)h0 | ((u32)h1 << 16);
      Ll[j] = (u32)l0 | ((u32)l1 << 16);
    }
    *(uint4*)(xh + i) = make_uint4(Hh[0], Hh[1], Hh[2], Hh[3]);
    *(uint4*)(xl + i) = make_uint4(Ll[0], Ll[1], Ll[2], Ll[3]);
  } else {
    int wb = bid - 2048;                    // [0,768): 256 64x64 tiles x 3 mats
    int z = wb >> 8;
    int rem = wb & 255;
    int by = (rem >> 4) * 64, bx = (rem & 15) * 64;
    const float* W = (z == 0) ? w0 : ((z == 1) ? w1 : w2);
    u16* th = ws + WT_HI_E + (size_t)z * (1u << 20);
    u16* tl = ws + WT_LO_E + (size_t)z * (1u << 20);
    __shared__ float tile[64][65];
    int tx = threadIdx.x & 15, ty = threadIdx.x >> 4;  // 16 x 16
#pragma unroll
    for (int i = 0; i < 4; i++) {
      int r = ty + i * 16;
      float4 v = *(const float4*)(W + (size_t)(by + r) * 1024 + bx + tx * 4);
      tile[r][tx * 4 + 0] = v.x;
      tile[r][tx * 4 + 1] = v.y;
      tile[r][tx * 4 + 2] = v.z;
      tile[r][tx * 4 + 3] = v.w;
    }
    __syncthreads();
    // transposed write: thread owns 8 consecutive k for one output row n
#pragma unroll
    for (int p = 0; p < 2; p++) {
      int t = threadIdx.x + 256 * p;
      int kc = t & 7, nl = t >> 3;  // kc: chunk of 8 k, nl in [0,64)
      u32 Hh[4], Ll[4];
#pragma unroll
      for (int u = 0; u < 4; u++) {
        float v0 = tile[kc * 8 + 2 * u][nl];      // = W[by+k][bx+nl]
        float v1 = tile[kc * 8 + 2 * u + 1][nl];
        u16 h0 = f2bf(v0);
        u16 h1 = f2bf(v1);
        u16 l0 = f2bf(v0 - bf16_f(h0));
        u16 l1 = f2bf(v1 - bf16_f(h1));
        Hh[u] = (u32)h0 | ((u32)h1 << 16);
        Ll[u] = (u32)l0 | ((u32)l1 << 16);
      }
      size_t o = (size_t)(bx + nl) * 1024 + by + kc * 8;
      *(uint4*)(th + o) = make_uint4(Hh[0], Hh[1], Hh[2], Hh[3]);
      *(uint4*)(tl + o) = make_uint4(Ll[0], Ll[1], Ll[2], Ll[3]);
    }
  }
}

// ---------------- projections: Y = X @ W, compensated bf16 MFMA ----------------
// 64(M)x128(N) tiles, grid 1536 = 8 xcd x 8 m x 8 n x 3 z, XCD-affine M.
__global__ __launch_bounds__(256, 4) void k_proj(u16* __restrict__ ws) {
  int id = blockIdx.x;
  int xcd = id & 7;
  int loc = id >> 3;            // 192 per XCD
  int m_loc = loc & 7;          // 8 M-blocks of 64 rows per XCD slice
  int rest = loc >> 3;          // 24 = 8 n x 3 z
  int n_blk = rest & 7, z = rest >> 3;
  int M0 = (xcd * 8 + m_loc) * 64;
  int N0 = n_blk * 128;

  const u16* Xh = ws + X_HI_E;
  const u16* Xl = ws + X_LO_E;
  const u16* Wh = ws + WT_HI_E + (size_t)z * (1u << 20);
  const u16* Wl = ws + WT_LO_E + (size_t)z * (1u << 20);
  u16* dsth = ws + ((z == 0) ? Q_HI_E : ((z == 1) ? K_HI_E : V_HI_E));
  u16* dstl = (z == 0) ? (ws + Q_LO_E) : ((z == 1) ? (ws + K_LO_E) : (u16*)0);

  __shared__ u16 smem[12288];  // 24 KB: staging in main loop, epilogue after
  u16* sXh = smem;             // 64x32
  u16* sXl = smem + 2048;
  u16* sWh = smem + 4096;      // 128x32
  u16* sWl = smem + 8192;

  int tid = threadIdx.x, lane = tid & 63, w = tid >> 6;
  int quad = lane >> 4, l16 = lane & 15;
  int mb = (w & 1) * 32, nb = (w >> 1) * 64;

  const f32x4 z4 = {0.f, 0.f, 0.f, 0.f};
  f32x4 acc[4][2];             // [d-tile][s-tile] for all z
#pragma unroll
  for (int j = 0; j < 4; j++)
#pragma unroll
    for (int i = 0; i < 2; i++) acc[j][i] = z4;

  int xrow = tid >> 2, xq8 = tid & 3;  // X staging: one 16B chunk/thread

  for (int kk = 0; kk < 1024; kk += 32) {
    __syncthreads();
    {
      size_t gx = (size_t)(M0 + xrow) * 1024 + kk + xq8 * 8;
      gload16(Xh + gx, &sXh[(size_t)(w * 16) * 32]);
      if (z != 2) gload16(Xl + gx, &sXl[(size_t)(w * 16) * 32]);
#pragma unroll
      for (int j = 0; j < 2; j++) {
        int c = tid + 256 * j;
        int row = c >> 2, q8 = c & 3;
        size_t gw = (size_t)(N0 + row) * 1024 + kk + q8 * 8;
        gload16(Wh + gw, &sWh[(size_t)(j * 64 + w * 16) * 32]);
        if (z != 2) gload16(Wl + gw, &sWl[(size_t)(j * 64 + w * 16) * 32]);
      }
    }
    __syncthreads();
    bf16x8 ah[2], bh[4];
#pragma unroll
    for (int i = 0; i < 2; i++)
      ah[i] = *(const bf16x8*)&sXh[(mb + i * 16 + l16) * 32 + quad * 8];
#pragma unroll
    for (int j = 0; j < 4; j++)
      bh[j] = *(const bf16x8*)&sWh[(nb + j * 16 + l16) * 32 + quad * 8];
    if (z != 2) {
      bf16x8 al[2], bl[4];
#pragma unroll
      for (int i = 0; i < 2; i++)
        al[i] = *(const bf16x8*)&sXl[(mb + i * 16 + l16) * 32 + quad * 8];
#pragma unroll
      for (int j = 0; j < 4; j++)
        bl[j] = *(const bf16x8*)&sWl[(nb + j * 16 + l16) * 32 + quad * 8];
      // swapped operands: C row <- W(d), C col <- X(s)
#pragma unroll
      for (int j = 0; j < 4; j++)
#pragma unroll
        for (int i = 0; i < 2; i++) {
          f32x4 c0 = acc[j][i];
          c0 = __builtin_amdgcn_mfma_f32_16x16x32_bf16(bh[j], ah[i], c0, 0, 0, 0);
          c0 = __builtin_amdgcn_mfma_f32_16x16x32_bf16(bh[j], al[i], c0, 0, 0, 0);
          c0 = __builtin_amdgcn_mfma_f32_16x16x32_bf16(bl[j], ah[i], c0, 0, 0, 0);
          acc[j][i] = c0;
        }
    } else {
#pragma unroll
      for (int j = 0; j < 4; j++)
#pragma unroll
        for (int i = 0; i < 2; i++)
          acc[j][i] = __builtin_amdgcn_mfma_f32_16x16x32_bf16(ah[i], bh[j], acc[j][i], 0, 0, 0);
    }
  }

  // ---- dense epilogue via LDS (staging area is dead; barrier fences it) ----
  __syncthreads();
  int b = M0 >> 11, S0 = M0 & 2047;        // batch, 64-aligned s-base of block

  if (z != 2) {
    // per-wave-private 4KB region: 32(s) x 64(d) tile, d-chunk XOR swizzle
    u16* my = smem + (size_t)w * 2048;
    int hh = (N0 + nb) >> 6;
    int sbase = S0 + mb;
    float qscale = (z == 0) ? (0.125f * 1.4426950408889634f) : 1.0f;
#pragma unroll
    for (int pass = 0; pass < 2; pass++) {
      u16* dst = pass ? dstl : dsth;
#pragma unroll
      for (int j = 0; j < 4; j++)
#pragma unroll
        for (int i = 0; i < 2; i++) {
          int dl = j * 16 + quad * 4;   // d_local: 4 consecutive (one uint2)
          int sl = i * 16 + l16;        // s_local in [0,32)
          u16 e[4];
#pragma unroll
          for (int r = 0; r < 4; r++) {
            float y = acc[j][i][r] * qscale;
            u16 hv = bf16_rne(y);
            e[r] = pass ? bf16_rne(y - bf16_f(hv)) : hv;
          }
          int elem = sl * 64 + (((dl >> 3) ^ (sl & 7)) << 3) + (dl & 7);
          *(uint2*)&my[elem] = make_uint2((u32)e[0] | ((u32)e[1] << 16),
                                          (u32)e[2] | ((u32)e[3] << 16));
        }
#pragma unroll
      for (int t = 0; t < 4; t++) {
        int sr = (lane >> 3) + t * 8;
        int p = lane & 7;
        int rc = (z == 1) ? p : (p ^ (sr & 7));
        uint4 v = *(const uint4*)&my[sr * 64 + rc * 8];
        size_t o = ((size_t)(hh * 2 + b) * 2048 + sbase + sr) * 64 + p * 8;
        *(uint4*)&dst[o] = v;
      }
    }
  } else {
    // V: block-shared [half][64 d][64 s] tiles (16 KB), s-chunk XOR swizzle
#pragma unroll
    for (int j = 0; j < 4; j++)
#pragma unroll
      for (int i = 0; i < 2; i++) {
        int dl = j * 16 + l16;                       // d within 64
        int s64 = mb + i * 16 + quad * 4;            // s within 64 (both waves)
        u16 e[4];
#pragma unroll
        for (int r = 0; r < 4; r++) e[r] = bf16_rne(acc[j][i][r]);
        int cp = ((s64 >> 3) & 7) ^ (dl & 7);
        int elem = (w >> 1) * 4096 + dl * 64 + (cp << 3) + (s64 & 7);
        *(uint2*)&smem[elem] = make_uint2((u32)e[0] | ((u32)e[1] << 16),
                                          (u32)e[2] | ((u32)e[3] << 16));
      }
    __syncthreads();  // both waves of a half wrote all s of its d-rows
    int half = w >> 1;
    int hh = (N0 + half * 64) >> 6;
#pragma unroll
    for (int t = 0; t < 4; t++) {
      int dr = (w & 1) * 32 + (lane >> 3) + t * 8;   // d-row within the half
      int p = lane & 7;
      uint4 v = *(const uint4*)&smem[half * 4096 + dr * 64 + p * 8];
      size_t o = ((size_t)(hh * 2 + b) * 64 + dr) * 2048 + S0 + p * 8;
      *(uint4*)&dsth[o] = v;
    }
  }
}

// ---------------- flash attention: split-KV (2 halves), round-3 body verbatim ----------------
// grid 1024 = 32 hb x 16 qb x 2 key-halves; 4 waves/block, 32 q/wave, 16 iters.
// Full K hi/lo + V in LDS (48 KB dbuf) -> 3 blocks/CU = 12 waves/CU (1.5x TLP
// vs single-pass). No per-lane gathers (round-6's poison). Each half writes raw
// (unnormalized) O + per-query (m,l); k_merge combines.
__global__ __launch_bounds__(256, 3) void k_attn(u16* __restrict__ ws,
                                                 float* __restrict__ out) {
  const u16* Qh = ws + Q_HI_E;
  const u16* Ql = ws + Q_LO_E;
  const u16* Kh = ws + K_HI_E;
  const u16* Kl = ws + K_LO_E;
  const u16* Vt = ws + V_HI_E;

  __shared__ u16 sKh[2][64][64], sKl[2][64][64], sVt[2][64][64];  // 48 KB

  int id = blockIdx.x;
  int hb = id & 31, qb = (id >> 5) & 15, half = id >> 9;  // id&7 = XCD affinity
  int kbase = half << 10;                                 // key offset 0 / 1024
  int tid = threadIdx.x, w = tid >> 6, lane = tid & 63;
  int l31 = lane & 31, h = lane >> 5;
  size_t base = (size_t)hb * (2048 * 64);
  int qw0 = qb * 128 + w * 32;

  int srow = lane >> 3, sch = lane & 7;  // staging: 8 rows x 128B per wave-instr

  auto stage = [&](int buf, int t) {
    int kt = kbase + t * 64;
#pragma unroll
    for (int b2 = 0; b2 < 2; b2++) {
      int rr = w * 16 + b2 * 8;
      size_t kg = base + (size_t)(kt + rr + srow) * 64 + sch * 8;
      gload16(Kh + kg, &sKh[buf][rr][0]);
      gload16(Kl + kg, &sKl[buf][rr][0]);
      size_t vg = base + (size_t)(rr + srow) * 2048 + kt + sch * 8;
      gload16(Vt + vg, &sVt[buf][rr][0]);
    }
  };

  stage(0, 0);

  // Q B-operand frags (n = query = l31, k-step ks: d = ks*16 + h*8)
  bf16x8 qh[4], ql[4];
#pragma unroll
  for (int ks = 0; ks < 4; ks++) {
    size_t off = base + (size_t)(qw0 + l31) * 64 + ks * 16 + h * 8;
    qh[ks] = *(const bf16x8*)(Qh + off);
    ql[ks] = *(const bf16x8*)(Ql + off);
  }

  f32x16 o[2];
#pragma unroll
  for (int i = 0; i < 16; i++) { o[0][i] = 0.f; o[1][i] = 0.f; }
  float mr = -1e30f, lr = 0.f;

  // A-operand read from a swizzled tile: row = mt*32 + l31, chunk = (ks*2+h)^(row&7)
  auto rdA = [&](const u16 t[64][64], int mt, int ks) -> bf16x8 {
    int ch = ((ks * 2 + h) ^ (l31 & 7)) * 8;
    return *(const bf16x8*)&t[mt * 32 + l31][ch];
  };

  for (int it = 0; it < 16; it++) {
    __syncthreads();
    if (it + 1 < 16) stage((it + 1) & 1, it + 1);
    int buf = it & 1;

    // S^T = K.Q^T (compensated): lane holds query l31, its h-half of 64 keys
    f32x16 sc[2];
#pragma unroll
    for (int i = 0; i < 16; i++) { sc[0][i] = 0.f; sc[1][i] = 0.f; }
#pragma unroll
    for (int ks = 0; ks < 4; ks++)
#pragma unroll
      for (int mt = 0; mt < 2; mt++) {
        bf16x8 kh = rdA(sKh[buf], mt, ks);
        bf16x8 kl = rdA(sKl[buf], mt, ks);
        sc[mt] = __builtin_amdgcn_mfma_f32_32x32x16_bf16(kh, qh[ks], sc[mt], 0, 0, 0);
        sc[mt] = __builtin_amdgcn_mfma_f32_32x32x16_bf16(kh, ql[ks], sc[mt], 0, 0, 0);
        sc[mt] = __builtin_amdgcn_mfma_f32_32x32x16_bf16(kl, qh[ks], sc[mt], 0, 0, 0);
      }

    // online softmax (log2 domain): per-lane scalar stats, 1 shfl max + 1 shfl sum
    float mx = sc[0][0];
#pragma unroll
    for (int i = 0; i < 16; i++) {
      mx = fmaxf(mx, sc[0][i]);
      mx = fmaxf(mx, sc[1][i]);
    }
    mx = fmaxf(mx, __shfl_xor(mx, 32));
    float mnew = fmaxf(mr, mx);
    float alpha = __ocml_native_exp2_f32(mr - mnew);
    mr = mnew;
    float rs = 0.f;
    u32 pk[2][8];
#pragma unroll
    for (int t = 0; t < 2; t++)
#pragma unroll
      for (int i = 0; i < 8; i++) {
        float p0 = __ocml_native_exp2_f32(sc[t][2 * i] - mnew);
        float p1 = __ocml_native_exp2_f32(sc[t][2 * i + 1] - mnew);
        rs += p0 + p1;
        u32 a = __float_as_uint(p0) + 0x8000u;
        u32 b = __float_as_uint(p1) + 0x8000u;
        pk[t][i] = __builtin_amdgcn_perm(b, a, 0x07060302u);  // [hi16(a)|hi16(b)]
      }
    rs += __shfl_xor(rs, 32);
    lr = lr * alpha + rs;
#pragma unroll
    for (int i = 0; i < 16; i++) {
      o[0][i] *= alpha;
      o[1][i] *= alpha;
    }

    // O^T += V^T . P^T : B-frag (k=key, n=query) assembled from S^T regs via xor-32
#pragma unroll
    for (int ks = 0; ks < 4; ks++) {
      int t = ks >> 1, c = ks & 1;
      u32 b0 = pk[t][c * 4 + 0], b1 = pk[t][c * 4 + 1];
      u32 b2 = pk[t][c * 4 + 2], b3 = pk[t][c * 4 + 3];
      u32 rA = (u32)__shfl_xor((int)(h ? b0 : b2), 32);
      u32 rB = (u32)__shfl_xor((int)(h ? b1 : b3), 32);
      uint4 fb = h ? make_uint4(rA, rB, b2, b3) : make_uint4(b0, b1, rA, rB);
      bf16x8 pfrag = *(bf16x8*)&fb;
#pragma unroll
      for (int mt = 0; mt < 2; mt++) {
        bf16x8 vb = rdA(sVt[buf], mt, ks);
        o[mt] = __builtin_amdgcn_mfma_f32_32x32x16_bf16(vb, pfrag, o[mt], 0, 0, 0);
      }
    }
  }

  // epilogue: RAW (unnormalized) O; half0 -> out, half1 -> ws byte 0 region.
  float* dst = (half == 0) ? out : (float*)ws;
  size_t grow = (size_t)hb * 2048 + qw0 + l31;
#pragma unroll
  for (int mt = 0; mt < 2; mt++)
#pragma unroll
    for (int g2 = 0; g2 < 4; g2++) {
      int d0 = mt * 32 + g2 * 8 + 4 * h;
      float4 v = make_float4(o[mt][g2 * 4 + 0], o[mt][g2 * 4 + 1],
                             o[mt][g2 * 4 + 2], o[mt][g2 * 4 + 3]);
      *(float4*)(dst + grow * 64 + d0) = v;
    }
  // per-query stats (identical across h by construction): one lane writes
  if (h == 0) {
    float2* ml = (float2*)((char*)ws + ML_BYTE);
    ml[(size_t)half * 65536 + grow] = make_float2(mr, lr);
  }
}

// ---------------- merge the two KV-halves ----------------
// out = (o0*2^(m0-M) + o1*2^(m1-M)) / (l0*2^(m0-M) + l1*2^(m1-M))
__global__ __launch_bounds__(256) void k_merge(u16* __restrict__ ws,
                                               float* __restrict__ out) {
  size_t g = (size_t)blockIdx.x * 256 + threadIdx.x;  // float4 index, 1,048,576 total
  size_t row = g >> 4;                                // hb*2048 + q
  const float2* ml = (const float2*)((const char*)ws + ML_BYTE);
  float2 a = ml[row];
  float2 b = ml[65536 + row];
  float M = fmaxf(a.x, b.x);
  float e0 = __ocml_native_exp2_f32(a.x - M);
  float e1 = __ocml_native_exp2_f32(b.x - M);
  float winv = 1.f / (a.y * e0 + b.y * e1);
  float4 p0 = ((const float4*)out)[g];
  float4 p1 = ((const float4*)(const void*)ws)[g];
  float4 r = make_float4((p0.x * e0 + p1.x * e1) * winv,
                         (p0.y * e0 + p1.y * e1) * winv,
                         (p0.z * e0 + p1.z * e1) * winv,
                         (p0.w * e0 + p1.w * e1) * winv);
  ((float4*)out)[g] = r;
}

extern "C" void kernel_launch(void* const* d_in, const int* in_sizes, int n_in,
                              void* d_out, int out_size, void* d_ws, size_t ws_size,
                              hipStream_t stream) {
  const float* X = (const float*)d_in[0];
  const float* Wq = (const float*)d_in[1];
  const float* Wk = (const float*)d_in[2];
  const float* Wv = (const float*)d_in[3];
  u16* ws = (u16*)d_ws;
  float* out = (float*)d_out;

  k_split<<<dim3(2816), dim3(256), 0, stream>>>(X, Wq, Wk, Wv, ws);
  k_proj<<<dim3(1536), dim3(256), 0, stream>>>(ws);
  k_attn<<<dim3(1024), dim3(256), 0, stream>>>(ws, out);
  k_merge<<<dim3(4096), dim3(256), 0, stream>>>(ws, out);
}

// Round 8
// 239.958 us; speedup vs baseline: 1.1034x; 1.0078x over previous
//
#include <hip/hip_runtime.h>

typedef unsigned short u16;
typedef unsigned int u32;
typedef __bf16 bf16x8 __attribute__((ext_vector_type(8)));
typedef float f32x4 __attribute__((ext_vector_type(4)));
typedef float f32x16 __attribute__((ext_vector_type(16)));

extern "C" __device__ float __ocml_native_exp2_f32(float);

// workspace offsets in u16 elements
#define WT_HI_E  ((size_t)0)             // 3 x 1M
#define WT_LO_E  ((size_t)3 << 20)
#define X_HI_E   ((size_t)6 << 20)       // 4M each below
#define X_LO_E   ((size_t)10 << 20)
#define Q_HI_E   ((size_t)14 << 20)
#define Q_LO_E   ((size_t)18 << 20)
#define K_HI_E   ((size_t)22 << 20)      // [hb][s][64] d-chunk-XOR-swizzled
#define K_LO_E   ((size_t)26 << 20)
#define V_HI_E   ((size_t)30 << 20)      // V^T [hb][d][2048], s-chunk-XOR-swizzled per 64-key block
// split-KV partials (regions dead after k_proj): half1 raw-O f32 at ws byte 0
// (16.8 MiB over WT+X_HI-start), per-query (m,l) float2 at ws byte 17 MiB.
#define ML_BYTE  (17u << 20)

__device__ __forceinline__ u16 bf16_rne(float x) {
  u32 u = __float_as_uint(x);
  u32 r = (u + 0x7fffu + ((u >> 16) & 1u)) >> 16;
  return (u16)r;
}
__device__ __forceinline__ float bf16_f(u16 h) {
  return __uint_as_float(((u32)h) << 16);
}
// native hw convert (rounding mode irrelevant for hi/lo splits: lo absorbs it)
__device__ __forceinline__ u16 f2bf(float x) {
  __bf16 b = (__bf16)x;
  return __builtin_bit_cast(u16, b);
}

__device__ __forceinline__ void gload16(const u16* g, u16* l) {
  __builtin_amdgcn_global_load_lds(
      (const __attribute__((address_space(1))) void*)g,
      (__attribute__((address_space(3))) void*)l, 16, 0, 0);
}

// ---------------- fused input prep: X split + W transpose/split ----------------
__global__ __launch_bounds__(256) void k_split(const float* __restrict__ X,
                                               const float* __restrict__ w0,
                                               const float* __restrict__ w1,
                                               const float* __restrict__ w2,
                                               u16* __restrict__ ws) {
  int bid = blockIdx.x;
  if (bid < 2048) {
    u16* xh = ws + X_HI_E;
    u16* xl = ws + X_LO_E;
    size_t i = ((size_t)bid * 256 + threadIdx.x) * 8;
    float4 a = *(const float4*)(X + i);
    float4 b = *(const float4*)(X + i + 4);
    float v[8] = {a.x, a.y, a.z, a.w, b.x, b.y, b.z, b.w};
    u32 Hh[4], Ll[4];
#pragma unroll
    for (int j = 0; j < 4; j++) {
      u16 h0 = f2bf(v[2 * j]);
      u16 h1 = f2bf(v[2 * j + 1]);
      u16 l0 = f2bf(v[2 * j] - bf16_f(h0));
      u16 l1 = f2bf(v[2 * j + 1] - bf16_f(h1));
      Hh[j] = (u32)h0 | ((u32)h1 << 16);
      Ll[j] = (u32)l0 | ((u32)l1 << 16);
    }
    *(uint4*)(xh + i) = make_uint4(Hh[0], Hh[1], Hh[2], Hh[3]);
    *(uint4*)(xl + i) = make_uint4(Ll[0], Ll[1], Ll[2], Ll[3]);
  } else {
    int wb = bid - 2048;                    // [0,768): 256 64x64 tiles x 3 mats
    int z = wb >> 8;
    int rem = wb & 255;
    int by = (rem >> 4) * 64, bx = (rem & 15) * 64;
    const float* W = (z == 0) ? w0 : ((z == 1) ? w1 : w2);
    u16* th = ws + WT_HI_E + (size_t)z * (1u << 20);
    u16* tl = ws + WT_LO_E + (size_t)z * (1u << 20);
    __shared__ float tile[64][65];
    int tx = threadIdx.x & 15, ty = threadIdx.x >> 4;  // 16 x 16
#pragma unroll
    for (int i = 0; i < 4; i++) {
      int r = ty + i * 16;
      float4 v = *(const float4*)(W + (size_t)(by + r) * 1024 + bx + tx * 4);
      tile[r][tx * 4 + 0] = v.x;
      tile[r][tx * 4 + 1] = v.y;
      tile[r][tx * 4 + 2] = v.z;
      tile[r][tx * 4 + 3] = v.w;
    }
    __syncthreads();
    // transposed write: thread owns 8 consecutive k for one output row n
#pragma unroll
    for (int p = 0; p < 2; p++) {
      int t = threadIdx.x + 256 * p;
      int kc = t & 7, nl = t >> 3;  // kc: chunk of 8 k, nl in [0,64)
      u32 Hh[4], Ll[4];
#pragma unroll
      for (int u = 0; u < 4; u++) {
        float v0 = tile[kc * 8 + 2 * u][nl];      // = W[by+k][bx+nl]
        float v1 = tile[kc * 8 + 2 * u + 1][nl];
        u16 h0 = f2bf(v0);
        u16 h1 = f2bf(v1);
        u16 l0 = f2bf(v0 - bf16_f(h0));
        u16 l1 = f2bf(v1 - bf16_f(h1));
        Hh[u] = (u32)h0 | ((u32)h1 << 16);
        Ll[u] = (u32)l0 | ((u32)l1 << 16);
      }
      size_t o = (size_t)(bx + nl) * 1024 + by + kc * 8;
      *(uint4*)(th + o) = make_uint4(Hh[0], Hh[1], Hh[2], Hh[3]);
      *(uint4*)(tl + o) = make_uint4(Ll[0], Ll[1], Ll[2], Ll[3]);
    }
  }
}

// ---------------- projections: Y = X @ W, compensated bf16 MFMA ----------------
// 64(M)x128(N) tiles, grid 1536 = 8 xcd x 8 m x 8 n x 3 z, XCD-affine M.
__global__ __launch_bounds__(256, 4) void k_proj(u16* __restrict__ ws) {
  int id = blockIdx.x;
  int xcd = id & 7;
  int loc = id >> 3;            // 192 per XCD
  int m_loc = loc & 7;          // 8 M-blocks of 64 rows per XCD slice
  int rest = loc >> 3;          // 24 = 8 n x 3 z
  int n_blk = rest & 7, z = rest >> 3;
  int M0 = (xcd * 8 + m_loc) * 64;
  int N0 = n_blk * 128;

  const u16* Xh = ws + X_HI_E;
  const u16* Xl = ws + X_LO_E;
  const u16* Wh = ws + WT_HI_E + (size_t)z * (1u << 20);
  const u16* Wl = ws + WT_LO_E + (size_t)z * (1u << 20);
  u16* dsth = ws + ((z == 0) ? Q_HI_E : ((z == 1) ? K_HI_E : V_HI_E));
  u16* dstl = (z == 0) ? (ws + Q_LO_E) : ((z == 1) ? (ws + K_LO_E) : (u16*)0);

  __shared__ u16 smem[12288];  // 24 KB: staging in main loop, epilogue after
  u16* sXh = smem;             // 64x32
  u16* sXl = smem + 2048;
  u16* sWh = smem + 4096;      // 128x32
  u16* sWl = smem + 8192;

  int tid = threadIdx.x, lane = tid & 63, w = tid >> 6;
  int quad = lane >> 4, l16 = lane & 15;
  int mb = (w & 1) * 32, nb = (w >> 1) * 64;

  const f32x4 z4 = {0.f, 0.f, 0.f, 0.f};
  f32x4 acc[4][2];             // [d-tile][s-tile] for all z
#pragma unroll
  for (int j = 0; j < 4; j++)
#pragma unroll
    for (int i = 0; i < 2; i++) acc[j][i] = z4;

  int xrow = tid >> 2, xq8 = tid & 3;  // X staging: one 16B chunk/thread

  for (int kk = 0; kk < 1024; kk += 32) {
    __syncthreads();
    {
      size_t gx = (size_t)(M0 + xrow) * 1024 + kk + xq8 * 8;
      gload16(Xh + gx, &sXh[(size_t)(w * 16) * 32]);
      if (z != 2) gload16(Xl + gx, &sXl[(size_t)(w * 16) * 32]);
#pragma unroll
      for (int j = 0; j < 2; j++) {
        int c = tid + 256 * j;
        int row = c >> 2, q8 = c & 3;
        size_t gw = (size_t)(N0 + row) * 1024 + kk + q8 * 8;
        gload16(Wh + gw, &sWh[(size_t)(j * 64 + w * 16) * 32]);
        if (z != 2) gload16(Wl + gw, &sWl[(size_t)(j * 64 + w * 16) * 32]);
      }
    }
    __syncthreads();
    bf16x8 ah[2], bh[4];
#pragma unroll
    for (int i = 0; i < 2; i++)
      ah[i] = *(const bf16x8*)&sXh[(mb + i * 16 + l16) * 32 + quad * 8];
#pragma unroll
    for (int j = 0; j < 4; j++)
      bh[j] = *(const bf16x8*)&sWh[(nb + j * 16 + l16) * 32 + quad * 8];
    if (z != 2) {
      bf16x8 al[2], bl[4];
#pragma unroll
      for (int i = 0; i < 2; i++)
        al[i] = *(const bf16x8*)&sXl[(mb + i * 16 + l16) * 32 + quad * 8];
#pragma unroll
      for (int j = 0; j < 4; j++)
        bl[j] = *(const bf16x8*)&sWl[(nb + j * 16 + l16) * 32 + quad * 8];
      // swapped operands: C row <- W(d), C col <- X(s)
#pragma unroll
      for (int j = 0; j < 4; j++)
#pragma unroll
        for (int i = 0; i < 2; i++) {
          f32x4 c0 = acc[j][i];
          c0 = __builtin_amdgcn_mfma_f32_16x16x32_bf16(bh[j], ah[i], c0, 0, 0, 0);
          c0 = __builtin_amdgcn_mfma_f32_16x16x32_bf16(bh[j], al[i], c0, 0, 0, 0);
          c0 = __builtin_amdgcn_mfma_f32_16x16x32_bf16(bl[j], ah[i], c0, 0, 0, 0);
          acc[j][i] = c0;
        }
    } else {
#pragma unroll
      for (int j = 0; j < 4; j++)
#pragma unroll
        for (int i = 0; i < 2; i++)
          acc[j][i] = __builtin_amdgcn_mfma_f32_16x16x32_bf16(ah[i], bh[j], acc[j][i], 0, 0, 0);
    }
  }

  // ---- dense epilogue via LDS (staging area is dead; barrier fences it) ----
  __syncthreads();
  int b = M0 >> 11, S0 = M0 & 2047;        // batch, 64-aligned s-base of block

  if (z != 2) {
    // per-wave-private 4KB region: 32(s) x 64(d) tile, d-chunk XOR swizzle
    u16* my = smem + (size_t)w * 2048;
    int hh = (N0 + nb) >> 6;
    int sbase = S0 + mb;
    float qscale = (z == 0) ? (0.125f * 1.4426950408889634f) : 1.0f;
#pragma unroll
    for (int pass = 0; pass < 2; pass++) {
      u16* dst = pass ? dstl : dsth;
#pragma unroll
      for (int j = 0; j < 4; j++)
#pragma unroll
        for (int i = 0; i < 2; i++) {
          int dl = j * 16 + quad * 4;   // d_local: 4 consecutive (one uint2)
          int sl = i * 16 + l16;        // s_local in [0,32)
          u16 e[4];
#pragma unroll
          for (int r = 0; r < 4; r++) {
            float y = acc[j][i][r] * qscale;
            u16 hv = bf16_rne(y);
            e[r] = pass ? bf16_rne(y - bf16_f(hv)) : hv;
          }
          int elem = sl * 64 + (((dl >> 3) ^ (sl & 7)) << 3) + (dl & 7);
          *(uint2*)&my[elem] = make_uint2((u32)e[0] | ((u32)e[1] << 16),
                                          (u32)e[2] | ((u32)e[3] << 16));
        }
#pragma unroll
      for (int t = 0; t < 4; t++) {
        int sr = (lane >> 3) + t * 8;
        int p = lane & 7;
        int rc = (z == 1) ? p : (p ^ (sr & 7));
        uint4 v = *(const uint4*)&my[sr * 64 + rc * 8];
        size_t o = ((size_t)(hh * 2 + b) * 2048 + sbase + sr) * 64 + p * 8;
        *(uint4*)&dst[o] = v;
      }
    }
  } else {
    // V: block-shared [half][64 d][64 s] tiles (16 KB), s-chunk XOR swizzle
#pragma unroll
    for (int j = 0; j < 4; j++)
#pragma unroll
      for (int i = 0; i < 2; i++) {
        int dl = j * 16 + l16;                       // d within 64
        int s64 = mb + i * 16 + quad * 4;            // s within 64 (both waves)
        u16 e[4];
#pragma unroll
        for (int r = 0; r < 4; r++) e[r] = bf16_rne(acc[j][i][r]);
        int cp = ((s64 >> 3) & 7) ^ (dl & 7);
        int elem = (w >> 1) * 4096 + dl * 64 + (cp << 3) + (s64 & 7);
        *(uint2*)&smem[elem] = make_uint2((u32)e[0] | ((u32)e[1] << 16),
                                          (u32)e[2] | ((u32)e[3] << 16));
      }
    __syncthreads();  // both waves of a half wrote all s of its d-rows
    int half = w >> 1;
    int hh = (N0 + half * 64) >> 6;
#pragma unroll
    for (int t = 0; t < 4; t++) {
      int dr = (w & 1) * 32 + (lane >> 3) + t * 8;   // d-row within the half
      int p = lane & 7;
      uint4 v = *(const uint4*)&smem[half * 4096 + dr * 64 + p * 8];
      size_t o = ((size_t)(hh * 2 + b) * 64 + dr) * 2048 + S0 + p * 8;
      *(uint4*)&dsth[o] = v;
    }
  }
}

// ---------------- flash attention: BQ=64/wave, K/V LDS reads amortized 2x ----------------
// grid 512 = 32 hb x 8 qb x 2 key-halves; 4 waves/block, 64 q/wave, 16 iters.
// DS-pipe is the measured bottleneck (per-CU shared; 4-way-conflicted rdA reads
// ~48us/CU at BQ=32). Each K/V fragment read now feeds TWO query-sets:
// QK = 6 MFMA per 2 reads, PV = 2 MFMA per read -> DS bytes/work halved.
// Raw O + (m,l) out; k_merge combines halves.
__global__ __launch_bounds__(256, 2) void k_attn(u16* __restrict__ ws,
                                                 float* __restrict__ out) {
  const u16* Qh = ws + Q_HI_E;
  const u16* Ql = ws + Q_LO_E;
  const u16* Kh = ws + K_HI_E;
  const u16* Kl = ws + K_LO_E;
  const u16* Vt = ws + V_HI_E;

  __shared__ u16 sKh[2][64][64], sKl[2][64][64], sVt[2][64][64];  // 48 KB

  int id = blockIdx.x;
  int hb = id & 31, qb = (id >> 5) & 7, half = id >> 8;  // id&7 = XCD affinity
  int kbase = half << 10;                                // key offset 0 / 1024
  int tid = threadIdx.x, w = tid >> 6, lane = tid & 63;
  int l31 = lane & 31, h = lane >> 5;
  size_t base = (size_t)hb * (2048 * 64);
  int qw0 = qb * 256 + w * 64;

  int srow = lane >> 3, sch = lane & 7;  // staging: 8 rows x 128B per wave-instr

  auto stage = [&](int buf, int t) {
    int kt = kbase + t * 64;
#pragma unroll
    for (int b2 = 0; b2 < 2; b2++) {
      int rr = w * 16 + b2 * 8;
      size_t kg = base + (size_t)(kt + rr + srow) * 64 + sch * 8;
      gload16(Kh + kg, &sKh[buf][rr][0]);
      gload16(Kl + kg, &sKl[buf][rr][0]);
      size_t vg = base + (size_t)(rr + srow) * 2048 + kt + sch * 8;
      gload16(Vt + vg, &sVt[buf][rr][0]);
    }
  };

  stage(0, 0);

  // Q B-operand frags, 2 query-sets (qs): n = qw0 + qs*32 + l31
  bf16x8 qh[2][4], ql[2][4];
#pragma unroll
  for (int qs = 0; qs < 2; qs++)
#pragma unroll
    for (int ks = 0; ks < 4; ks++) {
      size_t off = base + (size_t)(qw0 + qs * 32 + l31) * 64 + ks * 16 + h * 8;
      qh[qs][ks] = *(const bf16x8*)(Qh + off);
      ql[qs][ks] = *(const bf16x8*)(Ql + off);
    }

  f32x16 o[2][2];
#pragma unroll
  for (int qs = 0; qs < 2; qs++)
#pragma unroll
    for (int i = 0; i < 16; i++) { o[qs][0][i] = 0.f; o[qs][1][i] = 0.f; }
  float mr[2] = {-1e30f, -1e30f};
  float lr[2] = {0.f, 0.f};

  // A-operand read from a swizzled tile: row = mt*32 + l31, chunk = (ks*2+h)^(row&7)
  auto rdA = [&](const u16 t[64][64], int mt, int ks) -> bf16x8 {
    int ch = ((ks * 2 + h) ^ (l31 & 7)) * 8;
    return *(const bf16x8*)&t[mt * 32 + l31][ch];
  };

  for (int it = 0; it < 16; it++) {
    __syncthreads();
    if (it + 1 < 16) stage((it + 1) & 1, it + 1);
    int buf = it & 1;

    // S^T = K.Q^T (compensated), both query-sets share each K fragment read
    f32x16 sc[2][2];
#pragma unroll
    for (int qs = 0; qs < 2; qs++)
#pragma unroll
      for (int i = 0; i < 16; i++) { sc[qs][0][i] = 0.f; sc[qs][1][i] = 0.f; }
#pragma unroll
    for (int ks = 0; ks < 4; ks++)
#pragma unroll
      for (int mt = 0; mt < 2; mt++) {
        bf16x8 kh = rdA(sKh[buf], mt, ks);
        bf16x8 kl = rdA(sKl[buf], mt, ks);
        sc[0][mt] = __builtin_amdgcn_mfma_f32_32x32x16_bf16(kh, qh[0][ks], sc[0][mt], 0, 0, 0);
        sc[1][mt] = __builtin_amdgcn_mfma_f32_32x32x16_bf16(kh, qh[1][ks], sc[1][mt], 0, 0, 0);
        sc[0][mt] = __builtin_amdgcn_mfma_f32_32x32x16_bf16(kh, ql[0][ks], sc[0][mt], 0, 0, 0);
        sc[1][mt] = __builtin_amdgcn_mfma_f32_32x32x16_bf16(kh, ql[1][ks], sc[1][mt], 0, 0, 0);
        sc[0][mt] = __builtin_amdgcn_mfma_f32_32x32x16_bf16(kl, qh[0][ks], sc[0][mt], 0, 0, 0);
        sc[1][mt] = __builtin_amdgcn_mfma_f32_32x32x16_bf16(kl, qh[1][ks], sc[1][mt], 0, 0, 0);
      }

    // online softmax per query-set (log2 domain)
    u32 pk[2][2][8];
#pragma unroll
    for (int qs = 0; qs < 2; qs++) {
      float mx = sc[qs][0][0];
#pragma unroll
      for (int i = 0; i < 16; i++) {
        mx = fmaxf(mx, sc[qs][0][i]);
        mx = fmaxf(mx, sc[qs][1][i]);
      }
      mx = fmaxf(mx, __shfl_xor(mx, 32));
      float mnew = fmaxf(mr[qs], mx);
      float alpha = __ocml_native_exp2_f32(mr[qs] - mnew);
      mr[qs] = mnew;
      float rs = 0.f;
#pragma unroll
      for (int t = 0; t < 2; t++)
#pragma unroll
        for (int i = 0; i < 8; i++) {
          float p0 = __ocml_native_exp2_f32(sc[qs][t][2 * i] - mnew);
          float p1 = __ocml_native_exp2_f32(sc[qs][t][2 * i + 1] - mnew);
          rs += p0 + p1;
          u32 a = __float_as_uint(p0) + 0x8000u;
          u32 b = __float_as_uint(p1) + 0x8000u;
          pk[qs][t][i] = __builtin_amdgcn_perm(b, a, 0x07060302u);  // [hi16(a)|hi16(b)]
        }
      rs += __shfl_xor(rs, 32);
      lr[qs] = lr[qs] * alpha + rs;
#pragma unroll
      for (int i = 0; i < 16; i++) {
        o[qs][0][i] *= alpha;
        o[qs][1][i] *= alpha;
      }
    }

    // O^T += V^T . P^T : both query-sets share each V fragment read
#pragma unroll
    for (int ks = 0; ks < 4; ks++) {
      int t = ks >> 1, c = ks & 1;
      bf16x8 pf[2];
#pragma unroll
      for (int qs = 0; qs < 2; qs++) {
        u32 b0 = pk[qs][t][c * 4 + 0], b1 = pk[qs][t][c * 4 + 1];
        u32 b2 = pk[qs][t][c * 4 + 2], b3 = pk[qs][t][c * 4 + 3];
        u32 rA = (u32)__shfl_xor((int)(h ? b0 : b2), 32);
        u32 rB = (u32)__shfl_xor((int)(h ? b1 : b3), 32);
        uint4 fb = h ? make_uint4(rA, rB, b2, b3) : make_uint4(b0, b1, rA, rB);
        pf[qs] = *(bf16x8*)&fb;
      }
#pragma unroll
      for (int mt = 0; mt < 2; mt++) {
        bf16x8 vb = rdA(sVt[buf], mt, ks);
        o[0][mt] = __builtin_amdgcn_mfma_f32_32x32x16_bf16(vb, pf[0], o[0][mt], 0, 0, 0);
        o[1][mt] = __builtin_amdgcn_mfma_f32_32x32x16_bf16(vb, pf[1], o[1][mt], 0, 0, 0);
      }
    }
  }

  // epilogue: RAW (unnormalized) O; half0 -> out, half1 -> ws byte 0 region.
  float* dst = (half == 0) ? out : (float*)ws;
  float2* ml = (float2*)((char*)ws + ML_BYTE);
#pragma unroll
  for (int qs = 0; qs < 2; qs++) {
    size_t grow = (size_t)hb * 2048 + qw0 + qs * 32 + l31;
#pragma unroll
    for (int mt = 0; mt < 2; mt++)
#pragma unroll
      for (int g2 = 0; g2 < 4; g2++) {
        int d0 = mt * 32 + g2 * 8 + 4 * h;
        float4 v = make_float4(o[qs][mt][g2 * 4 + 0], o[qs][mt][g2 * 4 + 1],
                               o[qs][mt][g2 * 4 + 2], o[qs][mt][g2 * 4 + 3]);
        *(float4*)(dst + grow * 64 + d0) = v;
      }
    // per-query stats (identical across h by construction): one lane writes
    if (h == 0) ml[(size_t)half * 65536 + grow] = make_float2(mr[qs], lr[qs]);
  }
}

// ---------------- merge the two KV-halves ----------------
// out = (o0*2^(m0-M) + o1*2^(m1-M)) / (l0*2^(m0-M) + l1*2^(m1-M))
__global__ __launch_bounds__(256) void k_merge(u16* __restrict__ ws,
                                               float* __restrict__ out) {
  size_t g = (size_t)blockIdx.x * 256 + threadIdx.x;  // float4 index, 1,048,576 total
  size_t row = g >> 4;                                // hb*2048 + q
  const float2* ml = (const float2*)((const char*)ws + ML_BYTE);
  float2 a = ml[row];
  float2 b = ml[65536 + row];
  float M = fmaxf(a.x, b.x);
  float e0 = __ocml_native_exp2_f32(a.x - M);
  float e1 = __ocml_native_exp2_f32(b.x - M);
  float winv = 1.f / (a.y * e0 + b.y * e1);
  float4 p0 = ((const float4*)out)[g];
  float4 p1 = ((const float4*)(const void*)ws)[g];
  float4 r = make_float4((p0.x * e0 + p1.x * e1) * winv,
                         (p0.y * e0 + p1.y * e1) * winv,
                         (p0.z * e0 + p1.z * e1) * winv,
                         (p0.w * e0 + p1.w * e1) * winv);
  ((float4*)out)[g] = r;
}

extern "C" void kernel_launch(void* const* d_in, const int* in_sizes, int n_in,
                              void* d_out, int out_size, void* d_ws, size_t ws_size,
                              hipStream_t stream) {
  const float* X = (const float*)d_in[0];
  const float* Wq = (const float*)d_in[1];
  const float* Wk = (const float*)d_in[2];
  const float* Wv = (const float*)d_in[3];
  u16* ws = (u16*)d_ws;
  float* out = (float*)d_out;

  k_split<<<dim3(2816), dim3(256), 0, stream>>>(X, Wq, Wk, Wv, ws);
  k_proj<<<dim3(1536), dim3(256), 0, stream>>>(ws);
  k_attn<<<dim3(512), dim3(256), 0, stream>>>(ws, out);
  k_merge<<<dim3(4096), dim3(256), 0, stream>>>(ws, out);
}

// Round 9
// 226.299 us; speedup vs baseline: 1.1700x; 1.0604x over previous
//
#include <hip/hip_runtime.h>

typedef unsigned short u16;
typedef unsigned int u32;
typedef __bf16 bf16x8 __attribute__((ext_vector_type(8)));
typedef float f32x4 __attribute__((ext_vector_type(4)));
typedef float f32x16 __attribute__((ext_vector_type(16)));

extern "C" __device__ float __ocml_native_exp2_f32(float);

// workspace offsets in u16 elements (X hi/lo regions no longer used)
#define WT_HI_E  ((size_t)0)             // 3 x 1M
#define WT_LO_E  ((size_t)3 << 20)
#define Q_HI_E   ((size_t)14 << 20)
#define Q_LO_E   ((size_t)18 << 20)
#define K_HI_E   ((size_t)22 << 20)      // [hb][s][64] d-chunk-XOR-swizzled
#define K_LO_E   ((size_t)26 << 20)
#define V_HI_E   ((size_t)30 << 20)      // V^T [hb][d][2048], s-chunk-XOR-swizzled per 64-key block

__device__ __forceinline__ u16 bf16_rne(float x) {
  u32 u = __float_as_uint(x);
  u32 r = (u + 0x7fffu + ((u >> 16) & 1u)) >> 16;
  return (u16)r;
}
__device__ __forceinline__ float bf16_f(u16 h) {
  return __uint_as_float(((u32)h) << 16);
}
// native hw convert (rounding mode irrelevant for hi/lo splits: lo absorbs it)
__device__ __forceinline__ u16 f2bf(float x) {
  __bf16 b = (__bf16)x;
  return __builtin_bit_cast(u16, b);
}

__device__ __forceinline__ void gload16(const u16* g, u16* l) {
  __builtin_amdgcn_global_load_lds(
      (const __attribute__((address_space(1))) void*)g,
      (__attribute__((address_space(3))) void*)l, 16, 0, 0);
}

// ---------------- input prep: W transpose/split ONLY (X handled in k_proj) ----------------
// grid 768: 256 64x64 tiles x 3 mats; uint4 coalesced stores on transposed axis.
__global__ __launch_bounds__(256) void k_split(const float* __restrict__ w0,
                                               const float* __restrict__ w1,
                                               const float* __restrict__ w2,
                                               u16* __restrict__ ws) {
  int wb = blockIdx.x;                    // [0,768)
  int z = wb >> 8;
  int rem = wb & 255;
  int by = (rem >> 4) * 64, bx = (rem & 15) * 64;
  const float* W = (z == 0) ? w0 : ((z == 1) ? w1 : w2);
  u16* th = ws + WT_HI_E + (size_t)z * (1u << 20);
  u16* tl = ws + WT_LO_E + (size_t)z * (1u << 20);
  __shared__ float tile[64][65];
  int tx = threadIdx.x & 15, ty = threadIdx.x >> 4;  // 16 x 16
#pragma unroll
  for (int i = 0; i < 4; i++) {
    int r = ty + i * 16;
    float4 v = *(const float4*)(W + (size_t)(by + r) * 1024 + bx + tx * 4);
    tile[r][tx * 4 + 0] = v.x;
    tile[r][tx * 4 + 1] = v.y;
    tile[r][tx * 4 + 2] = v.z;
    tile[r][tx * 4 + 3] = v.w;
  }
  __syncthreads();
  // transposed write: thread owns 8 consecutive k for one output row n
#pragma unroll
  for (int p = 0; p < 2; p++) {
    int t = threadIdx.x + 256 * p;
    int kc = t & 7, nl = t >> 3;  // kc: chunk of 8 k, nl in [0,64)
    u32 Hh[4], Ll[4];
#pragma unroll
    for (int u = 0; u < 4; u++) {
      float v0 = tile[kc * 8 + 2 * u][nl];      // = W[by+k][bx+nl]
      float v1 = tile[kc * 8 + 2 * u + 1][nl];
      u16 h0 = f2bf(v0);
      u16 h1 = f2bf(v1);
      u16 l0 = f2bf(v0 - bf16_f(h0));
      u16 l1 = f2bf(v1 - bf16_f(h1));
      Hh[u] = (u32)h0 | ((u32)h1 << 16);
      Ll[u] = (u32)l0 | ((u32)l1 << 16);
    }
    size_t o = (size_t)(bx + nl) * 1024 + by + kc * 8;
    *(uint4*)(th + o) = make_uint4(Hh[0], Hh[1], Hh[2], Hh[3]);
    *(uint4*)(tl + o) = make_uint4(Ll[0], Ll[1], Ll[2], Ll[3]);
  }
}

// ---------------- projections: Y = X @ W, compensated bf16 MFMA ----------------
// 64(M)x128(N) tiles, grid 1536 = 8 xcd x 8 m x 8 n x 3 z, XCD-affine M.
// X staged as fp32 DIRECTLY from input (hi/lo split at fragment-read time) --
// eliminates the separate X-split kernel pass. Staging uses pre-swizzled global
// source + linear LDS dest (global_load_lds constraint): X chunk ^= row&7 (frag
// reads 2-way = free, was 8-way conflicted), W chunk ^= (row>>1)&3 (2-way).
// z=0 -> Q*(0.125*log2e) (hi+lo), z=1 -> K (hi+lo, d-chunk swizzled),
// z=2 -> V (hi only, transposed, s-chunk swizzled per 64-key block).
__global__ __launch_bounds__(256, 4) void k_proj(const float* __restrict__ X,
                                                 u16* __restrict__ ws) {
  int id = blockIdx.x;
  int xcd = id & 7;
  int loc = id >> 3;            // 192 per XCD
  int m_loc = loc & 7;          // 8 M-blocks of 64 rows per XCD slice
  int rest = loc >> 3;          // 24 = 8 n x 3 z
  int n_blk = rest & 7, z = rest >> 3;
  int M0 = (xcd * 8 + m_loc) * 64;
  int N0 = n_blk * 128;

  const u16* Wh = ws + WT_HI_E + (size_t)z * (1u << 20);
  const u16* Wl = ws + WT_LO_E + (size_t)z * (1u << 20);
  u16* dsth = ws + ((z == 0) ? Q_HI_E : ((z == 1) ? K_HI_E : V_HI_E));
  u16* dstl = (z == 0) ? (ws + Q_LO_E) : ((z == 1) ? (ws + K_LO_E) : (u16*)0);

  __shared__ u16 smem[12288];   // 24 KB: sX fp32 8KB | sWh 8KB | sWl 8KB
  float* sXf = (float*)smem;    // [64 rows][8 slots x 4 floats], slot-swizzled
  u16* sWh = smem + 4096;       // [128 rows][4 slots x 8 u16], slot-swizzled
  u16* sWl = smem + 8192;

  int tid = threadIdx.x, lane = tid & 63, w = tid >> 6;
  int quad = lane >> 4, l16 = lane & 15;
  int mb = (w & 1) * 32, nb = (w >> 1) * 64;

  const f32x4 z4 = {0.f, 0.f, 0.f, 0.f};
  f32x4 acc[4][2];             // [d-tile][s-tile] for all z
#pragma unroll
  for (int j = 0; j < 4; j++)
#pragma unroll
    for (int i = 0; i < 2; i++) acc[j][i] = z4;

  for (int kk = 0; kk < 1024; kk += 32) {
    __syncthreads();
    {
      // X fp32: 512 x 16B chunks (64 rows x 8), 2/thread. LDS slot q of row
      // holds global chunk q^(row&7)  (pre-swizzled source, linear dest).
#pragma unroll
      for (int j = 0; j < 2; j++) {
        int c = tid + 256 * j;
        int row = c >> 3, q = c & 7;
        int gq = q ^ (row & 7);
        const float* src = X + (size_t)(M0 + row) * 1024 + kk + gq * 4;
        gload16((const u16*)src, &smem[(size_t)(w * 64 + 256 * j) * 8]);
      }
      // W: 512 x 16B chunks (128 rows x 4), slot q holds global chunk
      // q^((row>>1)&3) -> frag reads spread over 8 bank-positions (2-way).
#pragma unroll
      for (int j = 0; j < 2; j++) {
        int c = tid + 256 * j;
        int row = c >> 2, q = c & 3;
        int gq = q ^ ((row >> 1) & 3);
        size_t gw = (size_t)(N0 + row) * 1024 + kk + gq * 8;
        gload16(Wh + gw, &sWh[(size_t)(w * 64 + 256 * j) * 8]);
        if (z != 2) gload16(Wl + gw, &sWl[(size_t)(w * 64 + 256 * j) * 8]);
      }
    }
    __syncthreads();

    // W hi frags: row = nb + j*16 + l16, k = quad*8..+7 at slot quad^((row>>1)&3)
    bf16x8 bh[4];
#pragma unroll
    for (int j = 0; j < 4; j++) {
      int row = nb + j * 16 + l16;
      bh[j] = *(const bf16x8*)&sWh[row * 32 + (quad ^ ((row >> 1) & 3)) * 8];
    }
    // X frags from fp32 (hi + lo on the fly): row = mb + i*16 + l16,
    // k-chunks quad*2, quad*2+1 at slots g^(row&7)
    bf16x8 ah[2], al[2];
#pragma unroll
    for (int i = 0; i < 2; i++) {
      int row = mb + i * 16 + l16;
      const float* rp = sXf + row * 32;
      int r7 = row & 7;
      f32x4 xa = *(const f32x4*)(rp + ((quad * 2) ^ r7) * 4);
      f32x4 xb = *(const f32x4*)(rp + ((quad * 2 + 1) ^ r7) * 4);
      bf16x8 hv, lv;
#pragma unroll
      for (int e = 0; e < 4; e++) {
        __bf16 h0 = (__bf16)xa[e];
        hv[e] = h0;
        lv[e] = (__bf16)(xa[e] - (float)h0);
        __bf16 h1 = (__bf16)xb[e];
        hv[4 + e] = h1;
        lv[4 + e] = (__bf16)(xb[e] - (float)h1);
      }
      ah[i] = hv;
      al[i] = lv;
    }

    if (z != 2) {
      bf16x8 bl[4];
#pragma unroll
      for (int j = 0; j < 4; j++) {
        int row = nb + j * 16 + l16;
        bl[j] = *(const bf16x8*)&sWl[row * 32 + (quad ^ ((row >> 1) & 3)) * 8];
      }
      // swapped operands: C row <- W(d), C col <- X(s)
#pragma unroll
      for (int j = 0; j < 4; j++)
#pragma unroll
        for (int i = 0; i < 2; i++) {
          f32x4 c0 = acc[j][i];
          c0 = __builtin_amdgcn_mfma_f32_16x16x32_bf16(bh[j], ah[i], c0, 0, 0, 0);
          c0 = __builtin_amdgcn_mfma_f32_16x16x32_bf16(bh[j], al[i], c0, 0, 0, 0);
          c0 = __builtin_amdgcn_mfma_f32_16x16x32_bf16(bl[j], ah[i], c0, 0, 0, 0);
          acc[j][i] = c0;
        }
    } else {
      // un-swapped: C row <- X(s), C col <- W(d); hi only
#pragma unroll
      for (int j = 0; j < 4; j++)
#pragma unroll
        for (int i = 0; i < 2; i++)
          acc[j][i] = __builtin_amdgcn_mfma_f32_16x16x32_bf16(ah[i], bh[j], acc[j][i], 0, 0, 0);
    }
  }

  // ---- dense epilogue via LDS (staging area is dead; barrier fences it) ----
  __syncthreads();
  int b = M0 >> 11, S0 = M0 & 2047;        // batch, 64-aligned s-base of block

  if (z != 2) {
    // per-wave-private 4KB region: 32(s) x 64(d) tile, d-chunk XOR swizzle
    u16* my = smem + (size_t)w * 2048;
    int hh = (N0 + nb) >> 6;
    int sbase = S0 + mb;
    float qscale = (z == 0) ? (0.125f * 1.4426950408889634f) : 1.0f;
#pragma unroll
    for (int pass = 0; pass < 2; pass++) {
      u16* dst = pass ? dstl : dsth;
#pragma unroll
      for (int j = 0; j < 4; j++)
#pragma unroll
        for (int i = 0; i < 2; i++) {
          int dl = j * 16 + quad * 4;   // d_local: 4 consecutive (one uint2)
          int sl = i * 16 + l16;        // s_local in [0,32)
          u16 e[4];
#pragma unroll
          for (int r = 0; r < 4; r++) {
            float y = acc[j][i][r] * qscale;
            u16 hv = bf16_rne(y);
            e[r] = pass ? bf16_rne(y - bf16_f(hv)) : hv;
          }
          int elem = sl * 64 + (((dl >> 3) ^ (sl & 7)) << 3) + (dl & 7);
          *(uint2*)&my[elem] = make_uint2((u32)e[0] | ((u32)e[1] << 16),
                                          (u32)e[2] | ((u32)e[3] << 16));
        }
#pragma unroll
      for (int t = 0; t < 4; t++) {
        int sr = (lane >> 3) + t * 8;
        int p = lane & 7;
        int rc = (z == 1) ? p : (p ^ (sr & 7));
        uint4 v = *(const uint4*)&my[sr * 64 + rc * 8];
        size_t o = ((size_t)(hh * 2 + b) * 2048 + sbase + sr) * 64 + p * 8;
        *(uint4*)&dst[o] = v;
      }
    }
  } else {
    // V: block-shared [half][64 d][64 s] tiles (16 KB), s-chunk XOR swizzle
#pragma unroll
    for (int j = 0; j < 4; j++)
#pragma unroll
      for (int i = 0; i < 2; i++) {
        int dl = j * 16 + l16;                       // d within 64
        int s64 = mb + i * 16 + quad * 4;            // s within 64 (both waves)
        u16 e[4];
#pragma unroll
        for (int r = 0; r < 4; r++) e[r] = bf16_rne(acc[j][i][r]);
        int cp = ((s64 >> 3) & 7) ^ (dl & 7);
        int elem = (w >> 1) * 4096 + dl * 64 + (cp << 3) + (s64 & 7);
        *(uint2*)&smem[elem] = make_uint2((u32)e[0] | ((u32)e[1] << 16),
                                          (u32)e[2] | ((u32)e[3] << 16));
      }
    __syncthreads();  // both waves of a half wrote all s of its d-rows
    int half = w >> 1;
    int hh = (N0 + half * 64) >> 6;
#pragma unroll
    for (int t = 0; t < 4; t++) {
      int dr = (w & 1) * 32 + (lane >> 3) + t * 8;   // d-row within the half
      int p = lane & 7;
      uint4 v = *(const uint4*)&smem[half * 4096 + dr * 64 + p * 8];
      size_t o = ((size_t)(hh * 2 + b) * 64 + dr) * 2048 + S0 + p * 8;
      *(uint4*)&dsth[o] = v;
    }
  }
}

// ---------------- flash attention: 32x32 MFMA, S^T in-register, dbuf (round-3) ----------------
// grid 512 (= 2 blocks/CU), 4 waves/block, 32 queries/wave (BQ=128).
__global__ __launch_bounds__(256, 2) void k_attn(u16* __restrict__ ws,
                                                 float* __restrict__ out) {
  const u16* Qh = ws + Q_HI_E;
  const u16* Ql = ws + Q_LO_E;
  const u16* Kh = ws + K_HI_E;
  const u16* Kl = ws + K_LO_E;
  const u16* Vt = ws + V_HI_E;

  __shared__ u16 sKh[2][64][64], sKl[2][64][64], sVt[2][64][64];  // 48 KB

  int id = blockIdx.x;
  int hb = id & 31, qb = id >> 5;  // id&7 = XCD: 4 hbs' K/V per XCD L2
  int tid = threadIdx.x, w = tid >> 6, lane = tid & 63;
  int l31 = lane & 31, h = lane >> 5;
  size_t base = (size_t)hb * (2048 * 64);
  int qw0 = qb * 128 + w * 32;

  int srow = lane >> 3, sch = lane & 7;  // staging: 8 rows x 128B per wave-instr

  auto stage = [&](int buf, int t) {
#pragma unroll
    for (int b2 = 0; b2 < 2; b2++) {
      int rr = w * 16 + b2 * 8;
      size_t kg = base + (size_t)(t * 64 + rr + srow) * 64 + sch * 8;
      gload16(Kh + kg, &sKh[buf][rr][0]);
      gload16(Kl + kg, &sKl[buf][rr][0]);
      size_t vg = base + (size_t)(rr + srow) * 2048 + t * 64 + sch * 8;
      gload16(Vt + vg, &sVt[buf][rr][0]);
    }
  };

  stage(0, 0);

  // Q B-operand frags (n = query = l31, k-step ks: d = ks*16 + h*8)
  bf16x8 qh[4], ql[4];
#pragma unroll
  for (int ks = 0; ks < 4; ks++) {
    size_t off = base + (size_t)(qw0 + l31) * 64 + ks * 16 + h * 8;
    qh[ks] = *(const bf16x8*)(Qh + off);
    ql[ks] = *(const bf16x8*)(Ql + off);
  }

  f32x16 o[2];
#pragma unroll
  for (int i = 0; i < 16; i++) { o[0][i] = 0.f; o[1][i] = 0.f; }
  float mr = -1e30f, lr = 0.f;

  // A-operand read from a swizzled tile: row = mt*32 + l31, chunk = (ks*2+h)^(row&7)
  auto rdA = [&](const u16 t[64][64], int mt, int ks) -> bf16x8 {
    int ch = ((ks * 2 + h) ^ (l31 & 7)) * 8;
    return *(const bf16x8*)&t[mt * 32 + l31][ch];
  };

  for (int it = 0; it < 32; it++) {
    __syncthreads();
    if (it + 1 < 32) stage((it + 1) & 1, it + 1);
    int buf = it & 1;

    // S^T = K.Q^T (compensated): lane holds query l31, its h-half of 64 keys
    f32x16 sc[2];
#pragma unroll
    for (int i = 0; i < 16; i++) { sc[0][i] = 0.f; sc[1][i] = 0.f; }
#pragma unroll
    for (int ks = 0; ks < 4; ks++)
#pragma unroll
      for (int mt = 0; mt < 2; mt++) {
        bf16x8 kh = rdA(sKh[buf], mt, ks);
        bf16x8 kl = rdA(sKl[buf], mt, ks);
        sc[mt] = __builtin_amdgcn_mfma_f32_32x32x16_bf16(kh, qh[ks], sc[mt], 0, 0, 0);
        sc[mt] = __builtin_amdgcn_mfma_f32_32x32x16_bf16(kh, ql[ks], sc[mt], 0, 0, 0);
        sc[mt] = __builtin_amdgcn_mfma_f32_32x32x16_bf16(kl, qh[ks], sc[mt], 0, 0, 0);
      }

    // online softmax (log2 domain): per-lane scalar stats, 1 shfl max + 1 shfl sum
    float mx = sc[0][0];
#pragma unroll
    for (int i = 0; i < 16; i++) {
      mx = fmaxf(mx, sc[0][i]);
      mx = fmaxf(mx, sc[1][i]);
    }
    mx = fmaxf(mx, __shfl_xor(mx, 32));
    float mnew = fmaxf(mr, mx);
    float alpha = __ocml_native_exp2_f32(mr - mnew);
    mr = mnew;
    float rs = 0.f;
    u32 pk[2][8];
#pragma unroll
    for (int t = 0; t < 2; t++)
#pragma unroll
      for (int i = 0; i < 8; i++) {
        float p0 = __ocml_native_exp2_f32(sc[t][2 * i] - mnew);
        float p1 = __ocml_native_exp2_f32(sc[t][2 * i + 1] - mnew);
        rs += p0 + p1;
        u32 a = __float_as_uint(p0) + 0x8000u;
        u32 b = __float_as_uint(p1) + 0x8000u;
        pk[t][i] = __builtin_amdgcn_perm(b, a, 0x07060302u);  // [hi16(a)|hi16(b)]
      }
    rs += __shfl_xor(rs, 32);
    lr = lr * alpha + rs;
#pragma unroll
    for (int i = 0; i < 16; i++) {
      o[0][i] *= alpha;
      o[1][i] *= alpha;
    }

    // O^T += V^T . P^T : B-frag (k=key, n=query) assembled from S^T regs via xor-32
#pragma unroll
    for (int ks = 0; ks < 4; ks++) {
      int t = ks >> 1, c = ks & 1;
      u32 b0 = pk[t][c * 4 + 0], b1 = pk[t][c * 4 + 1];
      u32 b2 = pk[t][c * 4 + 2], b3 = pk[t][c * 4 + 3];
      u32 rA = (u32)__shfl_xor((int)(h ? b0 : b2), 32);
      u32 rB = (u32)__shfl_xor((int)(h ? b1 : b3), 32);
      uint4 fb = h ? make_uint4(rA, rB, b2, b3) : make_uint4(b0, b1, rA, rB);
      bf16x8 pfrag = *(bf16x8*)&fb;
#pragma unroll
      for (int mt = 0; mt < 2; mt++) {
        bf16x8 vb = rdA(sVt[buf], mt, ks);
        o[mt] = __builtin_amdgcn_mfma_f32_32x32x16_bf16(vb, pfrag, o[mt], 0, 0, 0);
      }
    }
  }

  // epilogue: O^T C-layout col = query (per-lane lr), rows = d
  float inv = 1.f / lr;
  size_t grow = (size_t)hb * 2048 + qw0 + l31;
#pragma unroll
  for (int mt = 0; mt < 2; mt++)
#pragma unroll
    for (int g2 = 0; g2 < 4; g2++) {
      int d0 = mt * 32 + g2 * 8 + 4 * h;
      float4 v = make_float4(o[mt][g2 * 4 + 0] * inv, o[mt][g2 * 4 + 1] * inv,
                             o[mt][g2 * 4 + 2] * inv, o[mt][g2 * 4 + 3] * inv);
      *(float4*)(out + grow * 64 + d0) = v;
    }
}

extern "C" void kernel_launch(void* const* d_in, const int* in_sizes, int n_in,
                              void* d_out, int out_size, void* d_ws, size_t ws_size,
                              hipStream_t stream) {
  const float* X = (const float*)d_in[0];
  const float* Wq = (const float*)d_in[1];
  const float* Wk = (const float*)d_in[2];
  const float* Wv = (const float*)d_in[3];
  u16* ws = (u16*)d_ws;
  float* out = (float*)d_out;

  k_split<<<dim3(768), dim3(256), 0, stream>>>(Wq, Wk, Wv, ws);
  k_proj<<<dim3(1536), dim3(256), 0, stream>>>(X, ws);
  k_attn<<<dim3(512), dim3(256), 0, stream>>>(ws, out);
}